// Round 1
// baseline (627.580 us; speedup 1.0000x reference)
//
#include <hip/hip_runtime.h>
#include <hip/hip_bf16.h>

#define NN 50000
#define EE 800000
#define DD 128
#define F1 256   // H*HID after conv1
#define F2 128   // OUT

// ---------------- CSR build ----------------
__global__ void k_init(int* __restrict__ cnt) {
    int i = blockIdx.x * 256 + threadIdx.x;
    if (i < NN) cnt[i] = 1;            // self-loop pre-count
}

__global__ void k_hist(const int* __restrict__ dst, int* __restrict__ cnt) {
    int i = blockIdx.x * 256 + threadIdx.x;
    if (i < EE) atomicAdd(&cnt[dst[i]], 1);
}

__global__ void k_scan1(const int* __restrict__ cnt, int* __restrict__ out,
                        int* __restrict__ sums) {
    __shared__ int s[256];
    int i = blockIdx.x * 256 + threadIdx.x;
    int v = (i < NN) ? cnt[i] : 0;
    s[threadIdx.x] = v;
    __syncthreads();
    for (int off = 1; off < 256; off <<= 1) {
        int t = (threadIdx.x >= off) ? s[threadIdx.x - off] : 0;
        __syncthreads();
        s[threadIdx.x] += t;
        __syncthreads();
    }
    if (i < NN) out[i] = s[threadIdx.x] - v;   // exclusive
    if (threadIdx.x == 255) sums[blockIdx.x] = s[255];
}

__global__ void k_scan2(int* __restrict__ sums, int nb) {
    __shared__ int s[256];
    int v = (threadIdx.x < nb) ? sums[threadIdx.x] : 0;
    s[threadIdx.x] = v;
    __syncthreads();
    for (int off = 1; off < 256; off <<= 1) {
        int t = (threadIdx.x >= off) ? s[threadIdx.x - off] : 0;
        __syncthreads();
        s[threadIdx.x] += t;
        __syncthreads();
    }
    if (threadIdx.x < nb) sums[threadIdx.x] = s[threadIdx.x] - v;  // exclusive
}

__global__ void k_scan3(int* __restrict__ offsets, const int* __restrict__ sums,
                        int* __restrict__ cursor) {
    int i = blockIdx.x * 256 + threadIdx.x;
    if (i < NN) {
        int v = offsets[i] + sums[blockIdx.x];
        offsets[i] = v;
        cursor[i] = v;
    }
    if (blockIdx.x == 0 && threadIdx.x == 0) offsets[NN] = EE + NN;
}

__global__ void k_scatter(const int* __restrict__ esrc, const int* __restrict__ edst,
                          int* __restrict__ cursor, int* __restrict__ srcs) {
    int i = blockIdx.x * 256 + threadIdx.x;
    if (i < EE) {
        int pos = atomicAdd(&cursor[edst[i]], 1);
        srcs[pos] = esrc[i];
    } else if (i < EE + NN) {
        int n = i - EE;
        int pos = atomicAdd(&cursor[n], 1);
        srcs[pos] = n;
    }
}

// ---------------- GEMM: C[M x NCOL] = A[M x K] @ B[K x NCOL] (+bias) ----------------
// 64x64 block tile, full-K loop in 64-chunks, 4x4 acc per thread.
template<int K, bool GATHER>
__global__ __launch_bounds__(256) void k_gemm(
    const float* __restrict__ A, const float* __restrict__ B, int ldb,
    const int* __restrict__ idx, float* __restrict__ C, int ldc,
    const float* __restrict__ bias) {
    __shared__ float At[64][68];   // [k][m], +4 pad keeps 16B alignment
    __shared__ float Bs[64][64];   // [k][n]
    const int t  = threadIdx.x;
    const int lk = t & 15;         // k-quad for A load
    const int lm = t >> 4;         // 0..15
    const int ctm = t >> 4;        // m-group for compute
    const int ctn = t & 15;        // n-group for compute
    const int m0 = blockIdx.x * 64;
    const int n0 = blockIdx.y * 64;
    float acc[4][4] = {};
    for (int k0 = 0; k0 < K; k0 += 64) {
        #pragma unroll
        for (int p = 0; p < 4; ++p) {
            int ml  = p * 16 + lm;
            int row = m0 + ml;
            float4 v = make_float4(0.f, 0.f, 0.f, 0.f);
            if (row < NN) {
                int r = GATHER ? idx[row] : row;
                v = *(const float4*)(A + (size_t)r * K + k0 + lk * 4);
            }
            At[lk * 4 + 0][ml] = v.x;
            At[lk * 4 + 1][ml] = v.y;
            At[lk * 4 + 2][ml] = v.z;
            At[lk * 4 + 3][ml] = v.w;
        }
        #pragma unroll
        for (int q = 0; q < 4; ++q) {
            int kr = (t >> 4) + q * 16;
            float4 v = *(const float4*)(B + (size_t)(k0 + kr) * ldb + n0 + (t & 15) * 4);
            *(float4*)&Bs[kr][(t & 15) * 4] = v;
        }
        __syncthreads();
        #pragma unroll 16
        for (int k = 0; k < 64; ++k) {
            float4 a = *(const float4*)&At[k][ctm * 4];
            float4 b = *(const float4*)&Bs[k][ctn * 4];
            acc[0][0] += a.x * b.x; acc[0][1] += a.x * b.y; acc[0][2] += a.x * b.z; acc[0][3] += a.x * b.w;
            acc[1][0] += a.y * b.x; acc[1][1] += a.y * b.y; acc[1][2] += a.y * b.z; acc[1][3] += a.y * b.w;
            acc[2][0] += a.z * b.x; acc[2][1] += a.z * b.y; acc[2][2] += a.z * b.z; acc[2][3] += a.z * b.w;
            acc[3][0] += a.w * b.x; acc[3][1] += a.w * b.y; acc[3][2] += a.w * b.z; acc[3][3] += a.w * b.w;
        }
        __syncthreads();
    }
    float4 bb = make_float4(0.f, 0.f, 0.f, 0.f);
    if (bias) bb = *(const float4*)(bias + n0 + ctn * 4);
    #pragma unroll
    for (int i = 0; i < 4; ++i) {
        int m = m0 + ctm * 4 + i;
        if (m < NN) {
            float4 o = make_float4(acc[i][0] + bb.x, acc[i][1] + bb.y,
                                   acc[i][2] + bb.z, acc[i][3] + bb.w);
            *(float4*)(C + (size_t)m * ldc + n0 + ctn * 4) = o;
        }
    }
}

// ---------------- attention-logit dot products ----------------
__global__ __launch_bounds__(256) void k_al1(const float* __restrict__ h1,
                                             const float* __restrict__ a_src1,
                                             const float* __restrict__ a_dst1,
                                             float* __restrict__ a1s, float* __restrict__ a1d) {
    int n = blockIdx.x * 4 + (threadIdx.x >> 6);
    if (n >= NN) return;
    int lane = threadIdx.x & 63;
    float4 hv  = *(const float4*)(h1 + (size_t)n * F1 + lane * 4);
    float4 as  = *(const float4*)(a_src1 + lane * 4);
    float4 adv = *(const float4*)(a_dst1 + lane * 4);
    float ps = hv.x * as.x + hv.y * as.y + hv.z * as.z + hv.w * as.w;
    float pd = hv.x * adv.x + hv.y * adv.y + hv.z * adv.z + hv.w * adv.w;
    #pragma unroll
    for (int off = 1; off < 8; off <<= 1) {
        ps += __shfl_xor(ps, off);
        pd += __shfl_xor(pd, off);
    }
    if ((lane & 7) == 0) {
        a1s[n * 8 + (lane >> 3)] = ps;
        a1d[n * 8 + (lane >> 3)] = pd;
    }
}

__global__ __launch_bounds__(256) void k_al2(const float* __restrict__ h2,
                                             const float* __restrict__ a_src2,
                                             const float* __restrict__ a_dst2,
                                             float* __restrict__ a2s, float* __restrict__ a2d) {
    int n = blockIdx.x * 4 + (threadIdx.x >> 6);
    if (n >= NN) return;
    int lane = threadIdx.x & 63;
    float2 hv  = *(const float2*)(h2 + (size_t)n * F2 + lane * 2);
    float2 as  = *(const float2*)(a_src2 + lane * 2);
    float2 adv = *(const float2*)(a_dst2 + lane * 2);
    float ps = hv.x * as.x + hv.y * as.y;
    float pd = hv.x * adv.x + hv.y * adv.y;
    #pragma unroll
    for (int off = 1; off < 64; off <<= 1) {
        ps += __shfl_xor(ps, off);
        pd += __shfl_xor(pd, off);
    }
    if (lane == 0) { a2s[n] = ps; a2d[n] = pd; }
}

__device__ inline float lrelu(float x) { return x > 0.f ? x : 0.2f * x; }
__device__ inline float wave_max(float v) {
    #pragma unroll
    for (int off = 32; off; off >>= 1) v = fmaxf(v, __shfl_xor(v, off));
    return v;
}
__device__ inline float wave_sum(float v) {
    #pragma unroll
    for (int off = 32; off; off >>= 1) v += __shfl_xor(v, off);
    return v;
}

// ---------------- GAT aggregation, one wave per destination node ----------------
__global__ __launch_bounds__(256) void k_agg1(
    const int* __restrict__ offsets, const int* __restrict__ srcs,
    const float* __restrict__ h1, const float* __restrict__ a1s,
    const float* __restrict__ a1d, const float* __restrict__ b1,
    float* __restrict__ out1) {
    int d = blockIdx.x * 4 + (threadIdx.x >> 6);
    if (d >= NN) return;
    int lane = threadIdx.x & 63;
    int beg = offsets[d], end = offsets[d + 1];
    float ad[8], m[8], den[8];
    #pragma unroll
    for (int h = 0; h < 8; ++h) { ad[h] = a1d[d * 8 + h]; m[h] = -1e30f; den[h] = 0.f; }
    for (int i = beg + lane; i < end; i += 64) {
        int s = srcs[i];
        #pragma unroll
        for (int h = 0; h < 8; ++h) m[h] = fmaxf(m[h], lrelu(a1s[s * 8 + h] + ad[h]));
    }
    #pragma unroll
    for (int h = 0; h < 8; ++h) m[h] = wave_max(m[h]);
    for (int i = beg + lane; i < end; i += 64) {
        int s = srcs[i];
        #pragma unroll
        for (int h = 0; h < 8; ++h) den[h] += __expf(lrelu(a1s[s * 8 + h] + ad[h]) - m[h]);
    }
    #pragma unroll
    for (int h = 0; h < 8; ++h) den[h] = wave_sum(den[h]) + 1e-16f;
    int hh = lane >> 3;                         // head of channels [lane*4, lane*4+4)
    float mh = m[hh], dh = den[hh], adh = ad[hh];
    float4 acc = make_float4(0.f, 0.f, 0.f, 0.f);
    for (int i = beg; i < end; ++i) {
        int s = srcs[i];
        float alpha = __expf(lrelu(a1s[s * 8 + hh] + adh) - mh) / dh;
        float4 hv = *(const float4*)(h1 + (size_t)s * F1 + lane * 4);
        acc.x += alpha * hv.x; acc.y += alpha * hv.y;
        acc.z += alpha * hv.z; acc.w += alpha * hv.w;
    }
    float4 bb = *(const float4*)(b1 + lane * 4);
    acc.x += bb.x; acc.y += bb.y; acc.z += bb.z; acc.w += bb.w;
    *(float4*)(out1 + (size_t)d * F1 + lane * 4) = acc;
}

__global__ __launch_bounds__(256) void k_agg2(
    const int* __restrict__ offsets, const int* __restrict__ srcs,
    const float* __restrict__ h2, const float* __restrict__ a2s,
    const float* __restrict__ a2d, const float* __restrict__ b2,
    float* __restrict__ out2) {
    int d = blockIdx.x * 4 + (threadIdx.x >> 6);
    if (d >= NN) return;
    int lane = threadIdx.x & 63;
    int beg = offsets[d], end = offsets[d + 1];
    float ad = a2d[d];
    float m = -1e30f;
    for (int i = beg + lane; i < end; i += 64) m = fmaxf(m, lrelu(a2s[srcs[i]] + ad));
    m = wave_max(m);
    float den = 0.f;
    for (int i = beg + lane; i < end; i += 64) den += __expf(lrelu(a2s[srcs[i]] + ad) - m);
    den = wave_sum(den) + 1e-16f;
    float2 acc = make_float2(0.f, 0.f);
    for (int i = beg; i < end; ++i) {
        int s = srcs[i];
        float alpha = __expf(lrelu(a2s[s] + ad) - m) / den;
        float2 hv = *(const float2*)(h2 + (size_t)s * F2 + lane * 2);
        acc.x += alpha * hv.x; acc.y += alpha * hv.y;
    }
    float2 bb = *(const float2*)(b2 + lane * 2);
    acc.x += bb.x; acc.y += bb.y;
    *(float2*)(out2 + (size_t)d * F2 + lane * 2) = acc;
}

extern "C" void kernel_launch(void* const* d_in, const int* in_sizes, int n_in,
                              void* d_out, int out_size, void* d_ws, size_t ws_size,
                              hipStream_t stream) {
    const int*   x      = (const int*)d_in[0];
    const int*   edge   = (const int*)d_in[1];   // [2][E]
    const float* emb    = (const float*)d_in[2];
    const float* W1     = (const float*)d_in[3];
    const float* a_src1 = (const float*)d_in[4];
    const float* a_dst1 = (const float*)d_in[5];
    const float* b1     = (const float*)d_in[6];
    const float* W2     = (const float*)d_in[7];
    const float* a_src2 = (const float*)d_in[8];
    const float* a_dst2 = (const float*)d_in[9];
    const float* b2     = (const float*)d_in[10];
    const float* Wo     = (const float*)d_in[11];
    const float* bo     = (const float*)d_in[12];
    float* out = (float*)d_out;

    char* w = (char*)d_ws;
    auto alloc = [&](size_t bytes) {
        char* p = w;
        w += (bytes + 255) & ~(size_t)255;
        return p;
    };
    int*   offsets = (int*)alloc((NN + 1) * sizeof(int));
    int*   cursor  = (int*)alloc(NN * sizeof(int));
    int*   sums    = (int*)alloc(256 * sizeof(int));
    int*   srcs    = (int*)alloc((size_t)(EE + NN) * sizeof(int));
    float* h1      = (float*)alloc((size_t)NN * F1 * sizeof(float));
    float* out1    = (float*)alloc((size_t)NN * F1 * sizeof(float));
    float* a1s     = (float*)alloc((size_t)NN * 8 * sizeof(float));
    float* a1d     = (float*)alloc((size_t)NN * 8 * sizeof(float));
    float* h2   = h1;                       // h1 dead after agg1
    float* out2 = h1 + (size_t)NN * F2;     // disjoint from h2
    float* a2s  = a1s;
    float* a2d  = a1d;

    const int* esrc = edge;
    const int* edst = edge + EE;

    const int NB = (NN + 255) / 256;        // 196

    // CSR build (dst-sorted)
    k_init<<<NB, 256, 0, stream>>>(cursor);
    k_hist<<<(EE + 255) / 256, 256, 0, stream>>>(edst, cursor);
    k_scan1<<<NB, 256, 0, stream>>>(cursor, offsets, sums);
    k_scan2<<<1, 256, 0, stream>>>(sums, NB);
    k_scan3<<<NB, 256, 0, stream>>>(offsets, sums, cursor);
    k_scatter<<<(EE + NN + 255) / 256, 256, 0, stream>>>(esrc, edst, cursor, srcs);

    const int MT = (NN + 63) / 64;          // 782

    // conv1
    k_gemm<DD, true><<<dim3(MT, F1 / 64), 256, 0, stream>>>(emb, W1, F1, x, h1, F1, nullptr);
    k_al1<<<(NN + 3) / 4, 256, 0, stream>>>(h1, a_src1, a_dst1, a1s, a1d);
    k_agg1<<<(NN + 3) / 4, 256, 0, stream>>>(offsets, srcs, h1, a1s, a1d, b1, out1);

    // conv2
    k_gemm<F1, false><<<dim3(MT, F2 / 64), 256, 0, stream>>>(out1, W2, F2, nullptr, h2, F2, nullptr);
    k_al2<<<(NN + 3) / 4, 256, 0, stream>>>(h2, a_src2, a_dst2, a2s, a2d);
    k_agg2<<<(NN + 3) / 4, 256, 0, stream>>>(offsets, srcs, h2, a2s, a2d, b2, out2);

    // output linear
    k_gemm<F2, false><<<dim3(MT, F2 / 64), 256, 0, stream>>>(out2, Wo, F2, nullptr, out, F2, bo);
}

// Round 3
// 435.003 us; speedup vs baseline: 1.4427x; 1.4427x over previous
//
#include <hip/hip_runtime.h>
#include <hip/hip_bf16.h>

#define NN 50000
#define EE 800000
#define DD 128
#define F1 256   // H*HID after conv1
#define F2 128   // OUT

using short8  = __attribute__((ext_vector_type(8))) short;
using floatx4 = __attribute__((ext_vector_type(4))) float;

__device__ inline float bf2f(ushort u) { return __uint_as_float(((unsigned)u) << 16); }
__device__ inline ushort f2bf(float f) {
    unsigned u = __float_as_uint(f);
    u += 0x7fffu + ((u >> 16) & 1u);      // round-to-nearest-even
    return (ushort)(u >> 16);
}

// ---------------- CSR build ----------------
__global__ void k_init(int* __restrict__ cnt) {
    int i = blockIdx.x * 256 + threadIdx.x;
    if (i < NN) cnt[i] = 1;            // self-loop pre-count
}

__global__ void k_hist(const int* __restrict__ dst, int* __restrict__ cnt) {
    int i = blockIdx.x * 256 + threadIdx.x;
    if (i < EE) atomicAdd(&cnt[dst[i]], 1);
}

__global__ void k_scan1(const int* __restrict__ cnt, int* __restrict__ out,
                        int* __restrict__ sums) {
    __shared__ int s[256];
    int i = blockIdx.x * 256 + threadIdx.x;
    int v = (i < NN) ? cnt[i] : 0;
    s[threadIdx.x] = v;
    __syncthreads();
    for (int off = 1; off < 256; off <<= 1) {
        int t = (threadIdx.x >= off) ? s[threadIdx.x - off] : 0;
        __syncthreads();
        s[threadIdx.x] += t;
        __syncthreads();
    }
    if (i < NN) out[i] = s[threadIdx.x] - v;   // exclusive
    if (threadIdx.x == 255) sums[blockIdx.x] = s[255];
}

__global__ void k_scan2(int* __restrict__ sums, int nb) {
    __shared__ int s[256];
    int v = (threadIdx.x < nb) ? sums[threadIdx.x] : 0;
    s[threadIdx.x] = v;
    __syncthreads();
    for (int off = 1; off < 256; off <<= 1) {
        int t = (threadIdx.x >= off) ? s[threadIdx.x - off] : 0;
        __syncthreads();
        s[threadIdx.x] += t;
        __syncthreads();
    }
    if (threadIdx.x < nb) sums[threadIdx.x] = s[threadIdx.x] - v;  // exclusive
}

__global__ void k_scan3(int* __restrict__ offsets, const int* __restrict__ sums,
                        int* __restrict__ cursor) {
    int i = blockIdx.x * 256 + threadIdx.x;
    if (i < NN) {
        int v = offsets[i] + sums[blockIdx.x];
        offsets[i] = v;
        cursor[i] = v;
    }
    if (blockIdx.x == 0 && threadIdx.x == 0) offsets[NN] = EE + NN;
}

__global__ void k_scatter(const int* __restrict__ esrc, const int* __restrict__ edst,
                          int* __restrict__ cursor, int* __restrict__ srcs) {
    int i = blockIdx.x * 256 + threadIdx.x;
    if (i < EE) {
        int pos = atomicAdd(&cursor[edst[i]], 1);
        srcs[pos] = esrc[i];
    } else if (i < EE + NN) {
        int n = i - EE;
        int pos = atomicAdd(&cursor[n], 1);
        srcs[pos] = n;
    }
}

// ---------------- converts ----------------
// gather emb rows by x and convert to bf16: Ax[i][c] = bf16(emb[x[i]][c])
__global__ __launch_bounds__(256) void k_gather_emb(
    const int* __restrict__ x, const float* __restrict__ emb,
    ushort* __restrict__ Ax) {
    int row = blockIdx.x * 2 + (threadIdx.x >> 7);
    if (row >= NN) return;
    int c = threadIdx.x & 127;
    Ax[(size_t)row * DD + c] = f2bf(emb[(size_t)x[row] * DD + c]);
}

// W [K][NC] fp32 -> Wt [NC][K] bf16
template<int K, int NC>
__global__ void k_wt(const float* __restrict__ W, ushort* __restrict__ Wt) {
    int idx = blockIdx.x * 256 + threadIdx.x;
    if (idx >= K * NC) return;
    int k = idx / NC, n = idx % NC;
    Wt[(size_t)n * K + k] = f2bf(W[(size_t)k * NC + n]);
}

// ---------------- bf16 MFMA GEMM ----------------
// C[M x NCOL] = A[M x K](bf16) @ Bt[NCOL x K]^T(bf16), 128x128 tile, BK=64.
// FINAL: fp32 output + bias. else: bf16 output, no bias.
template<int K, bool FINAL>
__global__ __launch_bounds__(256, 2) void k_mfma_gemm(
    const ushort* __restrict__ A, const ushort* __restrict__ Bt,
    void* __restrict__ Cout, int ldc, const float* __restrict__ bias) {
    __shared__ ushort As[128][72];   // [m][k], row stride 144B (16B-aligned)
    __shared__ ushort Bs[128][72];   // [n][k]
    const int t    = threadIdx.x;
    const int lane = t & 63;
    const int w    = t >> 6;
    const int wr   = w >> 1, wc = w & 1;
    const int m0   = blockIdx.x * 128;
    const int n0   = blockIdx.y * 128;
    floatx4 acc[4][4] = {};
    for (int k0 = 0; k0 < K; k0 += 64) {
        #pragma unroll
        for (int p = 0; p < 4; ++p) {            // 4 * 2048 = 8192 elems = full 128x64 tile
            int linear = p * 2048 + t * 8;
            int row = linear >> 6;               // 0..127
            int col = linear & 63;
            short8 va = {};
            int gm = m0 + row;
            if (gm < NN) va = *(const short8*)(A + (size_t)gm * K + k0 + col);
            *(short8*)&As[row][col] = va;
            short8 vb = *(const short8*)(Bt + (size_t)(n0 + row) * K + k0 + col);
            *(short8*)&Bs[row][col] = vb;
        }
        __syncthreads();
        #pragma unroll
        for (int kk = 0; kk < 64; kk += 32) {
            const int q8 = (lane >> 4) * 8;
            short8 af[4], bf[4];
            #pragma unroll
            for (int i = 0; i < 4; ++i)
                af[i] = *(const short8*)&As[wr * 64 + i * 16 + (lane & 15)][kk + q8];
            #pragma unroll
            for (int j = 0; j < 4; ++j)
                bf[j] = *(const short8*)&Bs[wc * 64 + j * 16 + (lane & 15)][kk + q8];
            #pragma unroll
            for (int i = 0; i < 4; ++i)
                #pragma unroll
                for (int j = 0; j < 4; ++j)
                    acc[i][j] = __builtin_amdgcn_mfma_f32_16x16x32_bf16(
                        af[i], bf[j], acc[i][j], 0, 0, 0);
        }
        __syncthreads();
    }
    const int r0 = (lane >> 4) * 4;
    const int cc = lane & 15;
    #pragma unroll
    for (int i = 0; i < 4; ++i) {
        #pragma unroll
        for (int r = 0; r < 4; ++r) {
            int m = m0 + wr * 64 + i * 16 + r0 + r;
            if (m >= NN) continue;
            #pragma unroll
            for (int j = 0; j < 4; ++j) {
                int n = n0 + wc * 64 + j * 16 + cc;
                float v = acc[i][j][r];
                if (FINAL) ((float*)Cout)[(size_t)m * ldc + n] = v + bias[n];
                else       ((ushort*)Cout)[(size_t)m * ldc + n] = f2bf(v);
            }
        }
    }
}

// ---------------- attention-logit dot products (bf16 features) ----------------
__global__ __launch_bounds__(256) void k_al1(const ushort* __restrict__ h1,
                                             const float* __restrict__ a_src1,
                                             const float* __restrict__ a_dst1,
                                             float* __restrict__ a1s, float* __restrict__ a1d) {
    int n = blockIdx.x * 4 + (threadIdx.x >> 6);
    if (n >= NN) return;
    int lane = threadIdx.x & 63;
    ushort4 hu = *(const ushort4*)(h1 + (size_t)n * F1 + lane * 4);
    float4 hv = make_float4(bf2f(hu.x), bf2f(hu.y), bf2f(hu.z), bf2f(hu.w));
    float4 as  = *(const float4*)(a_src1 + lane * 4);
    float4 adv = *(const float4*)(a_dst1 + lane * 4);
    float ps = hv.x * as.x + hv.y * as.y + hv.z * as.z + hv.w * as.w;
    float pd = hv.x * adv.x + hv.y * adv.y + hv.z * adv.z + hv.w * adv.w;
    #pragma unroll
    for (int off = 1; off < 8; off <<= 1) {
        ps += __shfl_xor(ps, off);
        pd += __shfl_xor(pd, off);
    }
    if ((lane & 7) == 0) {
        a1s[n * 8 + (lane >> 3)] = ps;
        a1d[n * 8 + (lane >> 3)] = pd;
    }
}

__global__ __launch_bounds__(256) void k_al2(const ushort* __restrict__ h2,
                                             const float* __restrict__ a_src2,
                                             const float* __restrict__ a_dst2,
                                             float* __restrict__ a2s, float* __restrict__ a2d) {
    int n = blockIdx.x * 4 + (threadIdx.x >> 6);
    if (n >= NN) return;
    int lane = threadIdx.x & 63;
    ushort2 hu = *(const ushort2*)(h2 + (size_t)n * F2 + lane * 2);
    float2 hv = make_float2(bf2f(hu.x), bf2f(hu.y));
    float2 as  = *(const float2*)(a_src2 + lane * 2);
    float2 adv = *(const float2*)(a_dst2 + lane * 2);
    float ps = hv.x * as.x + hv.y * as.y;
    float pd = hv.x * adv.x + hv.y * adv.y;
    #pragma unroll
    for (int off = 1; off < 64; off <<= 1) {
        ps += __shfl_xor(ps, off);
        pd += __shfl_xor(pd, off);
    }
    if (lane == 0) { a2s[n] = ps; a2d[n] = pd; }
}

__device__ inline float lrelu(float x) { return x > 0.f ? x : 0.2f * x; }
__device__ inline float wave_max(float v) {
    #pragma unroll
    for (int off = 32; off; off >>= 1) v = fmaxf(v, __shfl_xor(v, off));
    return v;
}
__device__ inline float wave_sum(float v) {
    #pragma unroll
    for (int off = 32; off; off >>= 1) v += __shfl_xor(v, off);
    return v;
}

// ---------------- GAT aggregation, one wave per destination node ----------------
__global__ __launch_bounds__(256) void k_agg1(
    const int* __restrict__ offsets, const int* __restrict__ srcs,
    const ushort* __restrict__ h1, const float* __restrict__ a1s,
    const float* __restrict__ a1d, const float* __restrict__ b1,
    ushort* __restrict__ out1) {
    int d = blockIdx.x * 4 + (threadIdx.x >> 6);
    if (d >= NN) return;
    int lane = threadIdx.x & 63;
    int beg = offsets[d], end = offsets[d + 1];
    float ad[8], m[8], den[8];
    #pragma unroll
    for (int h = 0; h < 8; ++h) { ad[h] = a1d[d * 8 + h]; m[h] = -1e30f; den[h] = 0.f; }
    for (int i = beg + lane; i < end; i += 64) {
        int s = srcs[i];
        #pragma unroll
        for (int h = 0; h < 8; ++h) m[h] = fmaxf(m[h], lrelu(a1s[s * 8 + h] + ad[h]));
    }
    #pragma unroll
    for (int h = 0; h < 8; ++h) m[h] = wave_max(m[h]);
    for (int i = beg + lane; i < end; i += 64) {
        int s = srcs[i];
        #pragma unroll
        for (int h = 0; h < 8; ++h) den[h] += __expf(lrelu(a1s[s * 8 + h] + ad[h]) - m[h]);
    }
    #pragma unroll
    for (int h = 0; h < 8; ++h) den[h] = wave_sum(den[h]);
    int hh = lane >> 3;                         // head of channels [lane*4, lane*4+4)
    float mh = m[hh], adh = ad[hh];
    float rdh = 1.f / (den[hh] + 1e-16f);
    float4 acc = make_float4(0.f, 0.f, 0.f, 0.f);
    int i = beg;
    for (; i + 2 <= end; i += 2) {
        int s0 = srcs[i], s1 = srcs[i + 1];
        float l0 = a1s[s0 * 8 + hh], l1 = a1s[s1 * 8 + hh];
        ushort4 u0 = *(const ushort4*)(h1 + (size_t)s0 * F1 + lane * 4);
        ushort4 u1 = *(const ushort4*)(h1 + (size_t)s1 * F1 + lane * 4);
        float al0 = __expf(lrelu(l0 + adh) - mh) * rdh;
        float al1 = __expf(lrelu(l1 + adh) - mh) * rdh;
        acc.x += al0 * bf2f(u0.x) + al1 * bf2f(u1.x);
        acc.y += al0 * bf2f(u0.y) + al1 * bf2f(u1.y);
        acc.z += al0 * bf2f(u0.z) + al1 * bf2f(u1.z);
        acc.w += al0 * bf2f(u0.w) + al1 * bf2f(u1.w);
    }
    if (i < end) {
        int s0 = srcs[i];
        float al0 = __expf(lrelu(a1s[s0 * 8 + hh] + adh) - mh) * rdh;
        ushort4 u0 = *(const ushort4*)(h1 + (size_t)s0 * F1 + lane * 4);
        acc.x += al0 * bf2f(u0.x); acc.y += al0 * bf2f(u0.y);
        acc.z += al0 * bf2f(u0.z); acc.w += al0 * bf2f(u0.w);
    }
    float4 bb = *(const float4*)(b1 + lane * 4);
    ushort4 o;
    o.x = f2bf(acc.x + bb.x); o.y = f2bf(acc.y + bb.y);
    o.z = f2bf(acc.z + bb.z); o.w = f2bf(acc.w + bb.w);
    *(ushort4*)(out1 + (size_t)d * F1 + lane * 4) = o;
}

__global__ __launch_bounds__(256) void k_agg2(
    const int* __restrict__ offsets, const int* __restrict__ srcs,
    const ushort* __restrict__ h2, const float* __restrict__ a2s,
    const float* __restrict__ a2d, const float* __restrict__ b2,
    ushort* __restrict__ out2) {
    int d = blockIdx.x * 4 + (threadIdx.x >> 6);
    if (d >= NN) return;
    int lane = threadIdx.x & 63;
    int beg = offsets[d], end = offsets[d + 1];
    float ad = a2d[d];
    float m = -1e30f;
    for (int i = beg + lane; i < end; i += 64) m = fmaxf(m, lrelu(a2s[srcs[i]] + ad));
    m = wave_max(m);
    float den = 0.f;
    for (int i = beg + lane; i < end; i += 64) den += __expf(lrelu(a2s[srcs[i]] + ad) - m);
    den = wave_sum(den);
    float rden = 1.f / (den + 1e-16f);
    float2 acc = make_float2(0.f, 0.f);
    int i = beg;
    for (; i + 2 <= end; i += 2) {
        int s0 = srcs[i], s1 = srcs[i + 1];
        float l0 = a2s[s0], l1 = a2s[s1];
        ushort2 u0 = *(const ushort2*)(h2 + (size_t)s0 * F2 + lane * 2);
        ushort2 u1 = *(const ushort2*)(h2 + (size_t)s1 * F2 + lane * 2);
        float al0 = __expf(lrelu(l0 + ad) - m) * rden;
        float al1 = __expf(lrelu(l1 + ad) - m) * rden;
        acc.x += al0 * bf2f(u0.x) + al1 * bf2f(u1.x);
        acc.y += al0 * bf2f(u0.y) + al1 * bf2f(u1.y);
    }
    if (i < end) {
        int s0 = srcs[i];
        float al0 = __expf(lrelu(a2s[s0] + ad) - m) * rden;
        ushort2 u0 = *(const ushort2*)(h2 + (size_t)s0 * F2 + lane * 2);
        acc.x += al0 * bf2f(u0.x); acc.y += al0 * bf2f(u0.y);
    }
    float2 bb = *(const float2*)(b2 + lane * 2);
    ushort2 o;
    o.x = f2bf(acc.x + bb.x); o.y = f2bf(acc.y + bb.y);
    *(ushort2*)(out2 + (size_t)d * F2 + lane * 2) = o;
}

extern "C" void kernel_launch(void* const* d_in, const int* in_sizes, int n_in,
                              void* d_out, int out_size, void* d_ws, size_t ws_size,
                              hipStream_t stream) {
    const int*   x      = (const int*)d_in[0];
    const int*   edge   = (const int*)d_in[1];   // [2][E]
    const float* emb    = (const float*)d_in[2];
    const float* W1     = (const float*)d_in[3];
    const float* a_src1 = (const float*)d_in[4];
    const float* a_dst1 = (const float*)d_in[5];
    const float* b1     = (const float*)d_in[6];
    const float* W2     = (const float*)d_in[7];
    const float* a_src2 = (const float*)d_in[8];
    const float* a_dst2 = (const float*)d_in[9];
    const float* b2     = (const float*)d_in[10];
    const float* Wo     = (const float*)d_in[11];
    const float* bo     = (const float*)d_in[12];
    float* out = (float*)d_out;

    char* w = (char*)d_ws;
    auto alloc = [&](size_t bytes) {
        char* p = w;
        w += (bytes + 255) & ~(size_t)255;
        return p;
    };
    int*    offsets = (int*)alloc((NN + 1) * sizeof(int));
    int*    cursor  = (int*)alloc(NN * sizeof(int));
    int*    sums    = (int*)alloc(256 * sizeof(int));
    int*    srcs    = (int*)alloc((size_t)(EE + NN) * sizeof(int));
    ushort* Ax      = (ushort*)alloc((size_t)NN * DD * sizeof(ushort));
    ushort* W1t     = (ushort*)alloc((size_t)DD * F1 * sizeof(ushort));
    ushort* W2t     = (ushort*)alloc((size_t)F1 * F2 * sizeof(ushort));
    ushort* Wot     = (ushort*)alloc((size_t)F2 * F2 * sizeof(ushort));
    ushort* h1      = (ushort*)alloc((size_t)NN * F1 * sizeof(ushort));
    ushort* out1    = (ushort*)alloc((size_t)NN * F1 * sizeof(ushort));
    ushort* h2      = (ushort*)alloc((size_t)NN * F2 * sizeof(ushort));
    ushort* out2    = (ushort*)alloc((size_t)NN * F2 * sizeof(ushort));
    float*  a1s     = (float*)alloc((size_t)NN * 8 * sizeof(float));
    float*  a1d     = (float*)alloc((size_t)NN * 8 * sizeof(float));
    float*  a2s     = a1s;
    float*  a2d     = a1d;

    const int* esrc = edge;
    const int* edst = edge + EE;

    const int NB = (NN + 255) / 256;        // 196

    // CSR build (dst-sorted)
    k_init<<<NB, 256, 0, stream>>>(cursor);
    k_hist<<<(EE + 255) / 256, 256, 0, stream>>>(edst, cursor);
    k_scan1<<<NB, 256, 0, stream>>>(cursor, offsets, sums);
    k_scan2<<<1, 256, 0, stream>>>(sums, NB);
    k_scan3<<<NB, 256, 0, stream>>>(offsets, sums, cursor);
    k_scatter<<<(EE + NN + 255) / 256, 256, 0, stream>>>(esrc, edst, cursor, srcs);

    // converts (overlap-friendly, all tiny except gather)
    k_gather_emb<<<(NN + 1) / 2, 256, 0, stream>>>(x, emb, Ax);
    k_wt<DD, F1><<<(DD * F1 + 255) / 256, 256, 0, stream>>>(W1, W1t);
    k_wt<F1, F2><<<(F1 * F2 + 255) / 256, 256, 0, stream>>>(W2, W2t);
    k_wt<F2, F2><<<(F2 * F2 + 255) / 256, 256, 0, stream>>>(Wo, Wot);

    const int MT = (NN + 127) / 128;        // 391

    // conv1
    k_mfma_gemm<DD, false><<<dim3(MT, F1 / 128), 256, 0, stream>>>(Ax, W1t, h1, F1, nullptr);
    k_al1<<<(NN + 3) / 4, 256, 0, stream>>>(h1, a_src1, a_dst1, a1s, a1d);
    k_agg1<<<(NN + 3) / 4, 256, 0, stream>>>(offsets, srcs, h1, a1s, a1d, b1, out1);

    // conv2
    k_mfma_gemm<F1, false><<<dim3(MT, 1), 256, 0, stream>>>(out1, W2t, h2, F2, nullptr);
    k_al2<<<(NN + 3) / 4, 256, 0, stream>>>(h2, a_src2, a_dst2, a2s, a2d);
    k_agg2<<<(NN + 3) / 4, 256, 0, stream>>>(offsets, srcs, h2, a2s, a2d, b2, out2);

    // output linear (fp32 out + bias)
    k_mfma_gemm<F2, true><<<dim3(MT, 1), 256, 0, stream>>>(out2, Wot, out, F2, bo);
}

// Round 4
// 378.382 us; speedup vs baseline: 1.6586x; 1.1496x over previous
//
#include <hip/hip_runtime.h>
#include <hip/hip_bf16.h>

#define NN 50000
#define EE 800000
#define DD 128
#define F1 256   // H*HID after conv1
#define F2 128   // OUT

using short8  = __attribute__((ext_vector_type(8))) short;
using floatx4 = __attribute__((ext_vector_type(4))) float;

__device__ inline float bf2f(ushort u) { return __uint_as_float(((unsigned)u) << 16); }
__device__ inline ushort f2bf(float f) {
    unsigned u = __float_as_uint(f);
    u += 0x7fffu + ((u >> 16) & 1u);      // round-to-nearest-even
    return (ushort)(u >> 16);
}

// ---------------- fused prep: edge histogram + emb gather + weight transposes ----------------
#define HB ((EE + 255) / 256)          // 3125
#define GB ((NN + 1) / 2)              // 25000
#define W1B ((DD * F1 + 255) / 256)    // 128
#define W2B ((F1 * F2 + 255) / 256)    // 128

__global__ __launch_bounds__(256) void k_prep(
    const int* __restrict__ edst, int* __restrict__ cnt,
    const int* __restrict__ x, const float* __restrict__ emb, ushort* __restrict__ Ax,
    const float* __restrict__ W1, ushort* __restrict__ W1t,
    const float* __restrict__ W2, ushort* __restrict__ W2t,
    const float* __restrict__ Wo, ushort* __restrict__ Wot) {
    int b = blockIdx.x;
    if (b < HB) {
        int i = b * 256 + threadIdx.x;
        if (i < EE) atomicAdd(&cnt[edst[i]], 1);
    } else if (b < HB + GB) {
        int row = (b - HB) * 2 + (threadIdx.x >> 7);
        if (row < NN) {
            int c = threadIdx.x & 127;
            Ax[(size_t)row * DD + c] = f2bf(emb[(size_t)x[row] * DD + c]);
        }
    } else if (b < HB + GB + W1B) {
        int idx = (b - HB - GB) * 256 + threadIdx.x;
        int k = idx / F1, n = idx % F1;          // K=DD, NC=F1
        W1t[(size_t)n * DD + k] = f2bf(W1[(size_t)k * F1 + n]);
    } else if (b < HB + GB + W1B + W2B) {
        int idx = (b - HB - GB - W1B) * 256 + threadIdx.x;
        int k = idx / F2, n = idx % F2;          // K=F1, NC=F2
        W2t[(size_t)n * F1 + k] = f2bf(W2[(size_t)k * F2 + n]);
    } else {
        int idx = (b - HB - GB - W1B - W2B) * 256 + threadIdx.x;
        int k = idx / F2, n = idx % F2;          // K=F2, NC=F2
        Wot[(size_t)n * F2 + k] = f2bf(Wo[(size_t)k * F2 + n]);
    }
}

// ---------------- CSR scan + scatter ----------------
__global__ void k_scan1(const int* __restrict__ cnt, int* __restrict__ out,
                        int* __restrict__ sums) {
    __shared__ int s[256];
    int i = blockIdx.x * 256 + threadIdx.x;
    int v = (i < NN) ? cnt[i] + 1 : 0;   // +1 self-loop
    s[threadIdx.x] = v;
    __syncthreads();
    for (int off = 1; off < 256; off <<= 1) {
        int t = (threadIdx.x >= off) ? s[threadIdx.x - off] : 0;
        __syncthreads();
        s[threadIdx.x] += t;
        __syncthreads();
    }
    if (i < NN) out[i] = s[threadIdx.x] - v;   // exclusive
    if (threadIdx.x == 255) sums[blockIdx.x] = s[255];
}

__global__ void k_scan2(int* __restrict__ sums, int nb) {
    __shared__ int s[256];
    int v = (threadIdx.x < nb) ? sums[threadIdx.x] : 0;
    s[threadIdx.x] = v;
    __syncthreads();
    for (int off = 1; off < 256; off <<= 1) {
        int t = (threadIdx.x >= off) ? s[threadIdx.x - off] : 0;
        __syncthreads();
        s[threadIdx.x] += t;
        __syncthreads();
    }
    if (threadIdx.x < nb) sums[threadIdx.x] = s[threadIdx.x] - v;  // exclusive
}

__global__ void k_scan3(int* __restrict__ offsets, const int* __restrict__ sums,
                        int* __restrict__ cursor) {
    int i = blockIdx.x * 256 + threadIdx.x;
    if (i < NN) {
        int v = offsets[i] + sums[blockIdx.x];
        offsets[i] = v;
        cursor[i] = v;
    }
    if (blockIdx.x == 0 && threadIdx.x == 0) offsets[NN] = EE + NN;
}

__global__ void k_scatter(const int* __restrict__ esrc, const int* __restrict__ edst,
                          int* __restrict__ cursor, int* __restrict__ srcs) {
    int i = blockIdx.x * 256 + threadIdx.x;
    if (i < EE) {
        int pos = atomicAdd(&cursor[edst[i]], 1);
        srcs[pos] = esrc[i];
    } else if (i < EE + NN) {
        int n = i - EE;
        int pos = atomicAdd(&cursor[n], 1);
        srcs[pos] = n;
    }
}

// ---------------- bf16 MFMA GEMM ----------------
// C[M x NCOL] = A[M x K](bf16) @ Bt[NCOL x K]^T(bf16), 128x128 tile, BK=64.
template<int K, bool FINAL>
__global__ __launch_bounds__(256, 2) void k_mfma_gemm(
    const ushort* __restrict__ A, const ushort* __restrict__ Bt,
    void* __restrict__ Cout, int ldc, const float* __restrict__ bias) {
    __shared__ ushort As[128][72];   // [m][k]
    __shared__ ushort Bs[128][72];   // [n][k]
    const int t    = threadIdx.x;
    const int lane = t & 63;
    const int w    = t >> 6;
    const int wr   = w >> 1, wc = w & 1;
    const int m0   = blockIdx.x * 128;
    const int n0   = blockIdx.y * 128;
    floatx4 acc[4][4] = {};
    for (int k0 = 0; k0 < K; k0 += 64) {
        #pragma unroll
        for (int p = 0; p < 4; ++p) {            // 4*2048 = full 128x64 tile
            int linear = p * 2048 + t * 8;
            int row = linear >> 6;
            int col = linear & 63;
            short8 va = {};
            int gm = m0 + row;
            if (gm < NN) va = *(const short8*)(A + (size_t)gm * K + k0 + col);
            *(short8*)&As[row][col] = va;
            short8 vb = *(const short8*)(Bt + (size_t)(n0 + row) * K + k0 + col);
            *(short8*)&Bs[row][col] = vb;
        }
        __syncthreads();
        #pragma unroll
        for (int kk = 0; kk < 64; kk += 32) {
            const int q8 = (lane >> 4) * 8;
            short8 af[4], bf[4];
            #pragma unroll
            for (int i = 0; i < 4; ++i)
                af[i] = *(const short8*)&As[wr * 64 + i * 16 + (lane & 15)][kk + q8];
            #pragma unroll
            for (int j = 0; j < 4; ++j)
                bf[j] = *(const short8*)&Bs[wc * 64 + j * 16 + (lane & 15)][kk + q8];
            #pragma unroll
            for (int i = 0; i < 4; ++i)
                #pragma unroll
                for (int j = 0; j < 4; ++j)
                    acc[i][j] = __builtin_amdgcn_mfma_f32_16x16x32_bf16(
                        af[i], bf[j], acc[i][j], 0, 0, 0);
        }
        __syncthreads();
    }
    const int r0 = (lane >> 4) * 4;
    const int cc = lane & 15;
    #pragma unroll
    for (int i = 0; i < 4; ++i) {
        #pragma unroll
        for (int r = 0; r < 4; ++r) {
            int m = m0 + wr * 64 + i * 16 + r0 + r;
            if (m >= NN) continue;
            #pragma unroll
            for (int j = 0; j < 4; ++j) {
                int n = n0 + wc * 64 + j * 16 + cc;
                float v = acc[i][j][r];
                if (FINAL) ((float*)Cout)[(size_t)m * ldc + n] = v + bias[n];
                else       ((ushort*)Cout)[(size_t)m * ldc + n] = f2bf(v);
            }
        }
    }
}

// ---------------- attention-logit dot products ----------------
__global__ __launch_bounds__(256) void k_al1(const ushort* __restrict__ h1,
                                             const float* __restrict__ a_src1,
                                             const float* __restrict__ a_dst1,
                                             float* __restrict__ a1s, float* __restrict__ a1d) {
    int n = blockIdx.x * 4 + (threadIdx.x >> 6);
    if (n >= NN) return;
    int lane = threadIdx.x & 63;
    ushort4 hu = *(const ushort4*)(h1 + (size_t)n * F1 + lane * 4);
    float4 hv = make_float4(bf2f(hu.x), bf2f(hu.y), bf2f(hu.z), bf2f(hu.w));
    float4 as  = *(const float4*)(a_src1 + lane * 4);
    float4 adv = *(const float4*)(a_dst1 + lane * 4);
    float ps = hv.x * as.x + hv.y * as.y + hv.z * as.z + hv.w * as.w;
    float pd = hv.x * adv.x + hv.y * adv.y + hv.z * adv.z + hv.w * adv.w;
    #pragma unroll
    for (int off = 1; off < 8; off <<= 1) {
        ps += __shfl_xor(ps, off);
        pd += __shfl_xor(pd, off);
    }
    if ((lane & 7) == 0) {
        a1s[n * 8 + (lane >> 3)] = ps;
        a1d[n * 8 + (lane >> 3)] = pd;
    }
}

__global__ __launch_bounds__(256) void k_al2(const ushort* __restrict__ h2,
                                             const float* __restrict__ a_src2,
                                             const float* __restrict__ a_dst2,
                                             float* __restrict__ a2s, float* __restrict__ a2d) {
    int n = blockIdx.x * 4 + (threadIdx.x >> 6);
    if (n >= NN) return;
    int lane = threadIdx.x & 63;
    ushort2 hu = *(const ushort2*)(h2 + (size_t)n * F2 + lane * 2);
    float2 hv = make_float2(bf2f(hu.x), bf2f(hu.y));
    float2 as  = *(const float2*)(a_src2 + lane * 2);
    float2 adv = *(const float2*)(a_dst2 + lane * 2);
    float ps = hv.x * as.x + hv.y * as.y;
    float pd = hv.x * adv.x + hv.y * adv.y;
    #pragma unroll
    for (int off = 1; off < 64; off <<= 1) {
        ps += __shfl_xor(ps, off);
        pd += __shfl_xor(pd, off);
    }
    if (lane == 0) { a2s[n] = ps; a2d[n] = pd; }
}

__device__ inline float lrelu(float x) { return x > 0.f ? x : 0.2f * x; }

// ---------------- GAT aggregation, one wave per destination node ----------------
// Softmax phase: lane = edge_slot*8 + head; online softmax + 3-step butterfly.
// Channel phase: lane = head*8 + chan_grp; alphas precomputed per tile into LDS.
__global__ __launch_bounds__(256) void k_agg1(
    const int* __restrict__ offsets, const int* __restrict__ srcs,
    const ushort* __restrict__ h1, const float* __restrict__ a1s,
    const float* __restrict__ a1d, const float* __restrict__ b1,
    ushort* __restrict__ out1) {
    __shared__ float atab[4][512];   // [wave][edge*8+head]
    __shared__ int   stab[4][64];    // [wave][edge]
    const int w = threadIdx.x >> 6;
    const int d = blockIdx.x * 4 + w;
    if (d >= NN) return;
    const int lane = threadIdx.x & 63;
    const int beg = offsets[d], end = offsets[d + 1];
    const int e8 = lane >> 3, h8 = lane & 7;
    const float ad = a1d[d * 8 + h8];
    // online softmax over this head's logits, 8 edges/iter
    float m = -1e30f, den = 0.f;
    for (int i = beg + e8; i < end; i += 8) {
        int s = srcs[i];
        float v = lrelu(a1s[s * 8 + h8] + ad);
        float nm = fmaxf(m, v);
        den = den * __expf(m - nm) + __expf(v - nm);
        m = nm;
    }
    #pragma unroll
    for (int mask = 8; mask < 64; mask <<= 1) {
        float om = __shfl_xor(m, mask);
        float od = __shfl_xor(den, mask);
        float nm = fmaxf(m, om);
        den = den * __expf(m - nm) + od * __expf(om - nm);
        m = nm;
    }
    float rden = 1.f / (den + 1e-16f);
    // remap (m, rden) for channel phase: channel lane needs head = lane>>3,
    // which lives in any lane whose (lane&7) == that head.
    const int sl = ((lane & 7) << 3) | (lane >> 3);
    const float mh  = __shfl(m, sl);
    const float rdh = __shfl(rden, sl);
    float4 acc = make_float4(0.f, 0.f, 0.f, 0.f);
    const int hh = lane >> 3;
    for (int tb = beg; tb < end; tb += 64) {
        int cnt = min(64, end - tb);
        if (lane < cnt) stab[w][lane] = srcs[tb + lane];
        int np = cnt * 8;
        for (int p = lane; p < np; p += 64) {       // p&7 == h8 always
            int s = stab[w][p >> 3];
            float v = lrelu(a1s[s * 8 + h8] + ad);
            atab[w][p] = __expf(v - m) * rden;      // m, rden for head h8
        }
        for (int e = 0; e < cnt; ++e) {
            int s = stab[w][e];
            float alpha = atab[w][e * 8 + hh];
            ushort4 u = *(const ushort4*)(h1 + (size_t)s * F1 + lane * 4);
            acc.x += alpha * bf2f(u.x); acc.y += alpha * bf2f(u.y);
            acc.z += alpha * bf2f(u.z); acc.w += alpha * bf2f(u.w);
        }
    }
    (void)mh; (void)rdh;   // remapped stats (kept for clarity; alphas come from LDS)
    float4 bb = *(const float4*)(b1 + lane * 4);
    ushort4 o;
    o.x = f2bf(acc.x + bb.x); o.y = f2bf(acc.y + bb.y);
    o.z = f2bf(acc.z + bb.z); o.w = f2bf(acc.w + bb.w);
    *(ushort4*)(out1 + (size_t)d * F1 + lane * 4) = o;
}

__global__ __launch_bounds__(256) void k_agg2(
    const int* __restrict__ offsets, const int* __restrict__ srcs,
    const ushort* __restrict__ h2, const float* __restrict__ a2s,
    const float* __restrict__ a2d, const float* __restrict__ b2,
    ushort* __restrict__ out2) {
    __shared__ float atab[4][64];
    __shared__ int   stab[4][64];
    const int w = threadIdx.x >> 6;
    const int d = blockIdx.x * 4 + w;
    if (d >= NN) return;
    const int lane = threadIdx.x & 63;
    const int beg = offsets[d], end = offsets[d + 1];
    const float ad = a2d[d];
    float m = -1e30f, den = 0.f;
    for (int i = beg + lane; i < end; i += 64) {
        int s = srcs[i];
        float v = lrelu(a2s[s] + ad);
        float nm = fmaxf(m, v);
        den = den * __expf(m - nm) + __expf(v - nm);
        m = nm;
    }
    #pragma unroll
    for (int mask = 1; mask < 64; mask <<= 1) {
        float om = __shfl_xor(m, mask);
        float od = __shfl_xor(den, mask);
        float nm = fmaxf(m, om);
        den = den * __expf(m - nm) + od * __expf(om - nm);
        m = nm;
    }
    float rden = 1.f / (den + 1e-16f);
    float2 acc = make_float2(0.f, 0.f);
    for (int tb = beg; tb < end; tb += 64) {
        int cnt = min(64, end - tb);
        if (lane < cnt) {
            int s = srcs[tb + lane];
            stab[w][lane] = s;
            atab[w][lane] = __expf(lrelu(a2s[s] + ad) - m) * rden;
        }
        for (int e = 0; e < cnt; ++e) {
            int s = stab[w][e];
            float alpha = atab[w][e];
            ushort2 u = *(const ushort2*)(h2 + (size_t)s * F2 + lane * 2);
            acc.x += alpha * bf2f(u.x); acc.y += alpha * bf2f(u.y);
        }
    }
    float2 bb = *(const float2*)(b2 + lane * 2);
    ushort2 o;
    o.x = f2bf(acc.x + bb.x); o.y = f2bf(acc.y + bb.y);
    *(ushort2*)(out2 + (size_t)d * F2 + lane * 2) = o;
}

extern "C" void kernel_launch(void* const* d_in, const int* in_sizes, int n_in,
                              void* d_out, int out_size, void* d_ws, size_t ws_size,
                              hipStream_t stream) {
    const int*   x      = (const int*)d_in[0];
    const int*   edge   = (const int*)d_in[1];   // [2][E]
    const float* emb    = (const float*)d_in[2];
    const float* W1     = (const float*)d_in[3];
    const float* a_src1 = (const float*)d_in[4];
    const float* a_dst1 = (const float*)d_in[5];
    const float* b1     = (const float*)d_in[6];
    const float* W2     = (const float*)d_in[7];
    const float* a_src2 = (const float*)d_in[8];
    const float* a_dst2 = (const float*)d_in[9];
    const float* b2     = (const float*)d_in[10];
    const float* Wo     = (const float*)d_in[11];
    const float* bo     = (const float*)d_in[12];
    float* out = (float*)d_out;

    char* w = (char*)d_ws;
    auto alloc = [&](size_t bytes) {
        char* p = w;
        w += (bytes + 255) & ~(size_t)255;
        return p;
    };
    int*    offsets = (int*)alloc((NN + 1) * sizeof(int));
    int*    cursor  = (int*)alloc(NN * sizeof(int));
    int*    sums    = (int*)alloc(256 * sizeof(int));
    int*    srcs    = (int*)alloc((size_t)(EE + NN) * sizeof(int));
    ushort* Ax      = (ushort*)alloc((size_t)NN * DD * sizeof(ushort));
    ushort* W1t     = (ushort*)alloc((size_t)DD * F1 * sizeof(ushort));
    ushort* W2t     = (ushort*)alloc((size_t)F1 * F2 * sizeof(ushort));
    ushort* Wot     = (ushort*)alloc((size_t)F2 * F2 * sizeof(ushort));
    ushort* h1      = (ushort*)alloc((size_t)NN * F1 * sizeof(ushort));
    ushort* out1    = (ushort*)alloc((size_t)NN * F1 * sizeof(ushort));
    ushort* h2      = (ushort*)alloc((size_t)NN * F2 * sizeof(ushort));
    ushort* out2    = (ushort*)alloc((size_t)NN * F2 * sizeof(ushort));
    float*  a1s     = (float*)alloc((size_t)NN * 8 * sizeof(float));
    float*  a1d     = (float*)alloc((size_t)NN * 8 * sizeof(float));
    float*  a2s     = a1s;
    float*  a2d     = a1d;

    const int* esrc = edge;
    const int* edst = edge + EE;

    const int NB = (NN + 255) / 256;        // 196

    // CSR build + converts
    hipMemsetAsync(cursor, 0, NN * sizeof(int), stream);
    k_prep<<<HB + GB + W1B + W2B + ((F2 * F2 + 255) / 256), 256, 0, stream>>>(
        edst, cursor, x, emb, Ax, W1, W1t, W2, W2t, Wo, Wot);
    k_scan1<<<NB, 256, 0, stream>>>(cursor, offsets, sums);
    k_scan2<<<1, 256, 0, stream>>>(sums, NB);
    k_scan3<<<NB, 256, 0, stream>>>(offsets, sums, cursor);
    k_scatter<<<(EE + NN + 255) / 256, 256, 0, stream>>>(esrc, edst, cursor, srcs);

    const int MT = (NN + 127) / 128;        // 391

    // conv1
    k_mfma_gemm<DD, false><<<dim3(MT, F1 / 128), 256, 0, stream>>>(Ax, W1t, h1, F1, nullptr);
    k_al1<<<(NN + 3) / 4, 256, 0, stream>>>(h1, a_src1, a_dst1, a1s, a1d);
    k_agg1<<<(NN + 3) / 4, 256, 0, stream>>>(offsets, srcs, h1, a1s, a1d, b1, out1);

    // conv2
    k_mfma_gemm<F1, false><<<dim3(MT, 1), 256, 0, stream>>>(out1, W2t, h2, F2, nullptr);
    k_al2<<<(NN + 3) / 4, 256, 0, stream>>>(h2, a_src2, a_dst2, a2s, a2d);
    k_agg2<<<(NN + 3) / 4, 256, 0, stream>>>(offsets, srcs, h2, a2s, a2d, b2, out2);

    // output linear (fp32 out + bias)
    k_mfma_gemm<F2, true><<<dim3(MT, 1), 256, 0, stream>>>(out2, Wot, out, F2, bo);
}

// Round 5
// 366.436 us; speedup vs baseline: 1.7127x; 1.0326x over previous
//
#include <hip/hip_runtime.h>
#include <hip/hip_bf16.h>

#define NN 50000
#define EE 800000
#define DD 128
#define F1 256   // H*HID after conv1
#define F2 128   // OUT

using short8  = __attribute__((ext_vector_type(8))) short;
using floatx4 = __attribute__((ext_vector_type(4))) float;

__device__ inline float bf2f(ushort u) { return __uint_as_float(((unsigned)u) << 16); }
__device__ inline ushort f2bf(float f) {
    unsigned u = __float_as_uint(f);
    u += 0x7fffu + ((u >> 16) & 1u);      // round-to-nearest-even
    return (ushort)(u >> 16);
}

// ---------------- fused prep: edge histogram + emb gather + weight transposes ----------------
#define HB ((EE + 255) / 256)          // 3125
#define GB ((NN + 1) / 2)              // 25000
#define W1B ((DD * F1 + 255) / 256)    // 128
#define W2B ((F1 * F2 + 255) / 256)    // 128
#define WOB ((F2 * F2 + 255) / 256)    // 64

__global__ __launch_bounds__(256) void k_prep(
    const int* __restrict__ edst, int* __restrict__ cnt,
    const int* __restrict__ x, const float* __restrict__ emb, ushort* __restrict__ Ax,
    const float* __restrict__ W1, ushort* __restrict__ W1t,
    const float* __restrict__ W2, ushort* __restrict__ W2t,
    const float* __restrict__ Wo, ushort* __restrict__ Wot) {
    int b = blockIdx.x;
    if (b < HB) {
        int i = b * 256 + threadIdx.x;
        if (i < EE) atomicAdd(&cnt[edst[i]], 1);
    } else if (b < HB + GB) {
        int row = (b - HB) * 2 + (threadIdx.x >> 7);
        if (row < NN) {
            int c = threadIdx.x & 127;
            Ax[(size_t)row * DD + c] = f2bf(emb[(size_t)x[row] * DD + c]);
        }
    } else if (b < HB + GB + W1B) {
        int idx = (b - HB - GB) * 256 + threadIdx.x;
        int k = idx / F1, n = idx % F1;
        W1t[(size_t)n * DD + k] = f2bf(W1[(size_t)k * F1 + n]);
    } else if (b < HB + GB + W1B + W2B) {
        int idx = (b - HB - GB - W1B) * 256 + threadIdx.x;
        int k = idx / F2, n = idx % F2;
        W2t[(size_t)n * F1 + k] = f2bf(W2[(size_t)k * F2 + n]);
    } else {
        int idx = (b - HB - GB - W1B - W2B) * 256 + threadIdx.x;
        int k = idx / F2, n = idx % F2;
        Wot[(size_t)n * F2 + k] = f2bf(Wo[(size_t)k * F2 + n]);
    }
}

// ---------------- CSR scan + scatter ----------------
__global__ void k_scan1(const int* __restrict__ cnt, int* __restrict__ out,
                        int* __restrict__ sums) {
    __shared__ int s[256];
    int i = blockIdx.x * 256 + threadIdx.x;
    int v = (i < NN) ? cnt[i] + 1 : 0;   // +1 self-loop
    s[threadIdx.x] = v;
    __syncthreads();
    for (int off = 1; off < 256; off <<= 1) {
        int t = (threadIdx.x >= off) ? s[threadIdx.x - off] : 0;
        __syncthreads();
        s[threadIdx.x] += t;
        __syncthreads();
    }
    if (i < NN) out[i] = s[threadIdx.x] - v;   // exclusive
    if (threadIdx.x == 255) sums[blockIdx.x] = s[255];
}

// each block redundantly scans the 196 block sums, applies its own base
__global__ void k_scan3(int* __restrict__ offsets, const int* __restrict__ sums,
                        int* __restrict__ cursor, int nb) {
    __shared__ int s[256];
    int v = (threadIdx.x < nb) ? sums[threadIdx.x] : 0;
    s[threadIdx.x] = v;
    __syncthreads();
    for (int off = 1; off < 256; off <<= 1) {
        int t = (threadIdx.x >= off) ? s[threadIdx.x - off] : 0;
        __syncthreads();
        s[threadIdx.x] += t;
        __syncthreads();
    }
    int base = (blockIdx.x == 0) ? 0 : s[blockIdx.x - 1];
    int i = blockIdx.x * 256 + threadIdx.x;
    if (i < NN) {
        int o = offsets[i] + base;
        offsets[i] = o;
        cursor[i] = o;
    }
    if (blockIdx.x == 0 && threadIdx.x == 0) offsets[NN] = EE + NN;
}

__global__ void k_scatter(const int* __restrict__ esrc, const int* __restrict__ edst,
                          int* __restrict__ cursor, int* __restrict__ srcs) {
    int i = blockIdx.x * 256 + threadIdx.x;
    if (i < EE) {
        int pos = atomicAdd(&cursor[edst[i]], 1);
        srcs[pos] = esrc[i];
    } else if (i < EE + NN) {
        int n = i - EE;
        int pos = atomicAdd(&cursor[n], 1);
        srcs[pos] = n;
    }
}

// ---------------- bf16 MFMA GEMM with fused attention-logit epilogue ----------------
// C[M x NCOL] = A[M x K](bf16) @ Bt[NCOL x K]^T(bf16), 128x128 tile, BK=64.
// MODE 0: bf16 out.  MODE 1: bf16 out + 8-head AL (a per 32 cols -> a1s/a1d).
// MODE 2: bf16 out + 1-head AL over 128 cols (-> a2s/a2d).  MODE 3: fp32 out + bias.
template<int K, int MODE>
__global__ __launch_bounds__(256, 2) void k_mfma_gemm(
    const ushort* __restrict__ A, const ushort* __restrict__ Bt,
    void* __restrict__ Cout, int ldc, const float* __restrict__ bias,
    const float* __restrict__ avs, const float* __restrict__ avd,
    float* __restrict__ out_s, float* __restrict__ out_d) {
    __shared__ ushort As[128][72];   // [m][k]
    __shared__ ushort Bs[128][72];   // [n][k]
    __shared__ float als[2][128], ald[2][128];   // MODE 2 cross-wave combine
    const int t    = threadIdx.x;
    const int lane = t & 63;
    const int w    = t >> 6;
    const int wr   = w >> 1, wc = w & 1;
    const int m0   = blockIdx.x * 128;
    const int n0   = blockIdx.y * 128;
    floatx4 acc[4][4] = {};
    for (int k0 = 0; k0 < K; k0 += 64) {
        #pragma unroll
        for (int p = 0; p < 4; ++p) {            // 4*2048 = full 128x64 tile
            int linear = p * 2048 + t * 8;
            int row = linear >> 6;
            int col = linear & 63;
            short8 va = {};
            int gm = m0 + row;
            if (gm < NN) va = *(const short8*)(A + (size_t)gm * K + k0 + col);
            *(short8*)&As[row][col] = va;
            short8 vb = *(const short8*)(Bt + (size_t)(n0 + row) * K + k0 + col);
            *(short8*)&Bs[row][col] = vb;
        }
        __syncthreads();
        #pragma unroll
        for (int kk = 0; kk < 64; kk += 32) {
            const int q8 = (lane >> 4) * 8;
            short8 af[4], bf[4];
            #pragma unroll
            for (int i = 0; i < 4; ++i)
                af[i] = *(const short8*)&As[wr * 64 + i * 16 + (lane & 15)][kk + q8];
            #pragma unroll
            for (int j = 0; j < 4; ++j)
                bf[j] = *(const short8*)&Bs[wc * 64 + j * 16 + (lane & 15)][kk + q8];
            #pragma unroll
            for (int i = 0; i < 4; ++i)
                #pragma unroll
                for (int j = 0; j < 4; ++j)
                    acc[i][j] = __builtin_amdgcn_mfma_f32_16x16x32_bf16(
                        af[i], bf[j], acc[i][j], 0, 0, 0);
        }
        __syncthreads();
    }
    const int q  = lane >> 4;
    const int r0 = q * 4;
    const int cc = lane & 15;
    float as0, as1, as2, as3, ad0, ad1, ad2, ad3;
    if (MODE == 1 || MODE == 2) {
        as0 = avs[n0 + wc * 64 +  0 + cc]; ad0 = avd[n0 + wc * 64 +  0 + cc];
        as1 = avs[n0 + wc * 64 + 16 + cc]; ad1 = avd[n0 + wc * 64 + 16 + cc];
        as2 = avs[n0 + wc * 64 + 32 + cc]; ad2 = avd[n0 + wc * 64 + 32 + cc];
        as3 = avs[n0 + wc * 64 + 48 + cc]; ad3 = avd[n0 + wc * 64 + 48 + cc];
    }
    #pragma unroll
    for (int i = 0; i < 4; ++i) {
        #pragma unroll
        for (int r = 0; r < 4; ++r) {
            int m = m0 + wr * 64 + i * 16 + r0 + r;
            if (MODE == 1) {
                // two heads per 64-col wave-half: cols [0,32) -> gh0, [32,64) -> gh1
                float hs0 = acc[i][0][r] * as0 + acc[i][1][r] * as1;
                float hs1 = acc[i][2][r] * as2 + acc[i][3][r] * as3;
                float hd0 = acc[i][0][r] * ad0 + acc[i][1][r] * ad1;
                float hd1 = acc[i][2][r] * ad2 + acc[i][3][r] * ad3;
                #pragma unroll
                for (int mask = 1; mask < 16; mask <<= 1) {
                    hs0 += __shfl_xor(hs0, mask);
                    hs1 += __shfl_xor(hs1, mask);
                    hd0 += __shfl_xor(hd0, mask);
                    hd1 += __shfl_xor(hd1, mask);
                }
                if (cc == 0 && m < NN) {
                    int gh = (n0 >> 5) + wc * 2;
                    out_s[m * 8 + gh] = hs0;   out_s[m * 8 + gh + 1] = hs1;
                    out_d[m * 8 + gh] = hd0;   out_d[m * 8 + gh + 1] = hd1;
                }
            }
            if (MODE == 2) {
                float ps = acc[i][0][r] * as0 + acc[i][1][r] * as1
                         + acc[i][2][r] * as2 + acc[i][3][r] * as3;
                float pd = acc[i][0][r] * ad0 + acc[i][1][r] * ad1
                         + acc[i][2][r] * ad2 + acc[i][3][r] * ad3;
                #pragma unroll
                for (int mask = 1; mask < 16; mask <<= 1) {
                    ps += __shfl_xor(ps, mask);
                    pd += __shfl_xor(pd, mask);
                }
                if (cc == 0) {
                    int lr = wr * 64 + i * 16 + r0 + r;
                    als[wc][lr] = ps;
                    ald[wc][lr] = pd;
                }
            }
            if (m < NN) {
                #pragma unroll
                for (int j = 0; j < 4; ++j) {
                    int n = n0 + wc * 64 + j * 16 + cc;
                    float v = acc[i][j][r];
                    if (MODE == 3) ((float*)Cout)[(size_t)m * ldc + n] = v + bias[n];
                    else           ((ushort*)Cout)[(size_t)m * ldc + n] = f2bf(v);
                }
            }
        }
    }
    if (MODE == 2) {
        __syncthreads();
        if (t < 128) {
            int m = m0 + t;
            if (m < NN) {
                out_s[m] = als[0][t] + als[1][t];
                out_d[m] = ald[0][t] + ald[1][t];
            }
        }
    }
}

__device__ inline float lrelu(float x) { return x > 0.f ? x : 0.2f * x; }

// ---------------- GAT aggregation, one wave per destination node ----------------
__global__ __launch_bounds__(256) void k_agg1(
    const int* __restrict__ offsets, const int* __restrict__ srcs,
    const ushort* __restrict__ h1, const float* __restrict__ a1s,
    const float* __restrict__ a1d, const float* __restrict__ b1,
    ushort* __restrict__ out1) {
    __shared__ float atab[4][512];   // [wave][edge*8+head]
    __shared__ int   stab[4][64];    // [wave][edge]
    const int w = threadIdx.x >> 6;
    const int d = blockIdx.x * 4 + w;
    if (d >= NN) return;
    const int lane = threadIdx.x & 63;
    const int beg = offsets[d], end = offsets[d + 1];
    const int e8 = lane >> 3, h8 = lane & 7;
    const float ad = a1d[d * 8 + h8];
    // online softmax over this head's logits, 8 edges/iter
    float m = -1e30f, den = 0.f;
    for (int i = beg + e8; i < end; i += 8) {
        int s = srcs[i];
        float v = lrelu(a1s[s * 8 + h8] + ad);
        float nm = fmaxf(m, v);
        den = den * __expf(m - nm) + __expf(v - nm);
        m = nm;
    }
    #pragma unroll
    for (int mask = 8; mask < 64; mask <<= 1) {
        float om = __shfl_xor(m, mask);
        float od = __shfl_xor(den, mask);
        float nm = fmaxf(m, om);
        den = den * __expf(m - nm) + od * __expf(om - nm);
        m = nm;
    }
    float rden = 1.f / (den + 1e-16f);
    float4 acc = make_float4(0.f, 0.f, 0.f, 0.f);
    const int hh = lane >> 3;
    for (int tb = beg; tb < end; tb += 64) {
        int cnt = min(64, end - tb);
        if (lane < cnt) stab[w][lane] = srcs[tb + lane];
        int np = cnt * 8;
        for (int p = lane; p < np; p += 64) {       // p&7 == h8 always
            int s = stab[w][p >> 3];
            float v = lrelu(a1s[s * 8 + h8] + ad);
            atab[w][p] = __expf(v - m) * rden;
        }
        int e = 0;
        for (; e + 4 <= cnt; e += 4) {
            int s0 = stab[w][e], s1 = stab[w][e + 1];
            int s2 = stab[w][e + 2], s3 = stab[w][e + 3];
            ushort4 u0 = *(const ushort4*)(h1 + (size_t)s0 * F1 + lane * 4);
            ushort4 u1 = *(const ushort4*)(h1 + (size_t)s1 * F1 + lane * 4);
            ushort4 u2 = *(const ushort4*)(h1 + (size_t)s2 * F1 + lane * 4);
            ushort4 u3 = *(const ushort4*)(h1 + (size_t)s3 * F1 + lane * 4);
            float a0 = atab[w][(e + 0) * 8 + hh];
            float a1 = atab[w][(e + 1) * 8 + hh];
            float a2 = atab[w][(e + 2) * 8 + hh];
            float a3 = atab[w][(e + 3) * 8 + hh];
            acc.x += a0 * bf2f(u0.x) + a1 * bf2f(u1.x) + a2 * bf2f(u2.x) + a3 * bf2f(u3.x);
            acc.y += a0 * bf2f(u0.y) + a1 * bf2f(u1.y) + a2 * bf2f(u2.y) + a3 * bf2f(u3.y);
            acc.z += a0 * bf2f(u0.z) + a1 * bf2f(u1.z) + a2 * bf2f(u2.z) + a3 * bf2f(u3.z);
            acc.w += a0 * bf2f(u0.w) + a1 * bf2f(u1.w) + a2 * bf2f(u2.w) + a3 * bf2f(u3.w);
        }
        for (; e < cnt; ++e) {
            int s = stab[w][e];
            float alpha = atab[w][e * 8 + hh];
            ushort4 u = *(const ushort4*)(h1 + (size_t)s * F1 + lane * 4);
            acc.x += alpha * bf2f(u.x); acc.y += alpha * bf2f(u.y);
            acc.z += alpha * bf2f(u.z); acc.w += alpha * bf2f(u.w);
        }
    }
    float4 bb = *(const float4*)(b1 + lane * 4);
    ushort4 o;
    o.x = f2bf(acc.x + bb.x); o.y = f2bf(acc.y + bb.y);
    o.z = f2bf(acc.z + bb.z); o.w = f2bf(acc.w + bb.w);
    *(ushort4*)(out1 + (size_t)d * F1 + lane * 4) = o;
}

__global__ __launch_bounds__(256) void k_agg2(
    const int* __restrict__ offsets, const int* __restrict__ srcs,
    const ushort* __restrict__ h2, const float* __restrict__ a2s,
    const float* __restrict__ a2d, const float* __restrict__ b2,
    ushort* __restrict__ out2) {
    __shared__ float atab[4][64];
    __shared__ int   stab[4][64];
    const int w = threadIdx.x >> 6;
    const int d = blockIdx.x * 4 + w;
    if (d >= NN) return;
    const int lane = threadIdx.x & 63;
    const int beg = offsets[d], end = offsets[d + 1];
    const float ad = a2d[d];
    float m = -1e30f, den = 0.f;
    for (int i = beg + lane; i < end; i += 64) {
        int s = srcs[i];
        float v = lrelu(a2s[s] + ad);
        float nm = fmaxf(m, v);
        den = den * __expf(m - nm) + __expf(v - nm);
        m = nm;
    }
    #pragma unroll
    for (int mask = 1; mask < 64; mask <<= 1) {
        float om = __shfl_xor(m, mask);
        float od = __shfl_xor(den, mask);
        float nm = fmaxf(m, om);
        den = den * __expf(m - nm) + od * __expf(om - nm);
        m = nm;
    }
    float rden = 1.f / (den + 1e-16f);
    float2 acc = make_float2(0.f, 0.f);
    for (int tb = beg; tb < end; tb += 64) {
        int cnt = min(64, end - tb);
        if (lane < cnt) {
            int s = srcs[tb + lane];
            stab[w][lane] = s;
            atab[w][lane] = __expf(lrelu(a2s[s] + ad) - m) * rden;
        }
        int e = 0;
        for (; e + 4 <= cnt; e += 4) {
            int s0 = stab[w][e], s1 = stab[w][e + 1];
            int s2 = stab[w][e + 2], s3 = stab[w][e + 3];
            ushort2 u0 = *(const ushort2*)(h2 + (size_t)s0 * F2 + lane * 2);
            ushort2 u1 = *(const ushort2*)(h2 + (size_t)s1 * F2 + lane * 2);
            ushort2 u2 = *(const ushort2*)(h2 + (size_t)s2 * F2 + lane * 2);
            ushort2 u3 = *(const ushort2*)(h2 + (size_t)s3 * F2 + lane * 2);
            float a0 = atab[w][e + 0], a1 = atab[w][e + 1];
            float a2 = atab[w][e + 2], a3 = atab[w][e + 3];
            acc.x += a0 * bf2f(u0.x) + a1 * bf2f(u1.x) + a2 * bf2f(u2.x) + a3 * bf2f(u3.x);
            acc.y += a0 * bf2f(u0.y) + a1 * bf2f(u1.y) + a2 * bf2f(u2.y) + a3 * bf2f(u3.y);
        }
        for (; e < cnt; ++e) {
            int s = stab[w][e];
            float alpha = atab[w][e];
            ushort2 u = *(const ushort2*)(h2 + (size_t)s * F2 + lane * 2);
            acc.x += alpha * bf2f(u.x); acc.y += alpha * bf2f(u.y);
        }
    }
    float2 bb = *(const float2*)(b2 + lane * 2);
    ushort2 o;
    o.x = f2bf(acc.x + bb.x); o.y = f2bf(acc.y + bb.y);
    *(ushort2*)(out2 + (size_t)d * F2 + lane * 2) = o;
}

extern "C" void kernel_launch(void* const* d_in, const int* in_sizes, int n_in,
                              void* d_out, int out_size, void* d_ws, size_t ws_size,
                              hipStream_t stream) {
    const int*   x      = (const int*)d_in[0];
    const int*   edge   = (const int*)d_in[1];   // [2][E]
    const float* emb    = (const float*)d_in[2];
    const float* W1     = (const float*)d_in[3];
    const float* a_src1 = (const float*)d_in[4];
    const float* a_dst1 = (const float*)d_in[5];
    const float* b1     = (const float*)d_in[6];
    const float* W2     = (const float*)d_in[7];
    const float* a_src2 = (const float*)d_in[8];
    const float* a_dst2 = (const float*)d_in[9];
    const float* b2     = (const float*)d_in[10];
    const float* Wo     = (const float*)d_in[11];
    const float* bo     = (const float*)d_in[12];
    float* out = (float*)d_out;

    char* w = (char*)d_ws;
    auto alloc = [&](size_t bytes) {
        char* p = w;
        w += (bytes + 255) & ~(size_t)255;
        return p;
    };
    int*    offsets = (int*)alloc((NN + 1) * sizeof(int));
    int*    cursor  = (int*)alloc(NN * sizeof(int));
    int*    sums    = (int*)alloc(256 * sizeof(int));
    int*    srcs    = (int*)alloc((size_t)(EE + NN) * sizeof(int));
    ushort* Ax      = (ushort*)alloc((size_t)NN * DD * sizeof(ushort));
    ushort* W1t     = (ushort*)alloc((size_t)DD * F1 * sizeof(ushort));
    ushort* W2t     = (ushort*)alloc((size_t)F1 * F2 * sizeof(ushort));
    ushort* Wot     = (ushort*)alloc((size_t)F2 * F2 * sizeof(ushort));
    ushort* h1      = (ushort*)alloc((size_t)NN * F1 * sizeof(ushort));
    ushort* out1    = (ushort*)alloc((size_t)NN * F1 * sizeof(ushort));
    ushort* h2      = (ushort*)alloc((size_t)NN * F2 * sizeof(ushort));
    ushort* out2    = (ushort*)alloc((size_t)NN * F2 * sizeof(ushort));
    float*  a1s     = (float*)alloc((size_t)NN * 8 * sizeof(float));
    float*  a1d     = (float*)alloc((size_t)NN * 8 * sizeof(float));
    float*  a2s     = a1s;
    float*  a2d     = a1d;

    const int* esrc = edge;
    const int* edst = edge + EE;

    const int NB = (NN + 255) / 256;        // 196

    // CSR build + converts
    hipMemsetAsync(cursor, 0, NN * sizeof(int), stream);
    k_prep<<<HB + GB + W1B + W2B + WOB, 256, 0, stream>>>(
        edst, cursor, x, emb, Ax, W1, W1t, W2, W2t, Wo, Wot);
    k_scan1<<<NB, 256, 0, stream>>>(cursor, offsets, sums);
    k_scan3<<<NB, 256, 0, stream>>>(offsets, sums, cursor, NB);
    k_scatter<<<(EE + NN + 255) / 256, 256, 0, stream>>>(esrc, edst, cursor, srcs);

    const int MT = (NN + 127) / 128;        // 391

    // conv1 (GEMM + fused al1)
    k_mfma_gemm<DD, 1><<<dim3(MT, F1 / 128), 256, 0, stream>>>(
        Ax, W1t, h1, F1, nullptr, a_src1, a_dst1, a1s, a1d);
    k_agg1<<<(NN + 3) / 4, 256, 0, stream>>>(offsets, srcs, h1, a1s, a1d, b1, out1);

    // conv2 (GEMM + fused al2)
    k_mfma_gemm<F1, 2><<<dim3(MT, 1), 256, 0, stream>>>(
        out1, W2t, h2, F2, nullptr, a_src2, a_dst2, a2s, a2d);
    k_agg2<<<(NN + 3) / 4, 256, 0, stream>>>(offsets, srcs, h2, a2s, a2d, b2, out2);

    // output linear (fp32 out + bias)
    k_mfma_gemm<F2, 3><<<dim3(MT, 1), 256, 0, stream>>>(
        out2, Wot, out, F2, bo, nullptr, nullptr, nullptr, nullptr);
}